// Round 16
// baseline (307.868 us; speedup 1.0000x reference)
//
#include <hip/hip_runtime.h>
#include <hip/hip_bf16.h>
#include <math.h>

#define N_EMBD   1024
#define N_HEAD   16
#define HEAD_DIM 64
#define BATCH    2
#define TSEQ     2048
#define RANK     16
#define LORA_SCALE 2.0f
#define M_TOTAL  (BATCH * TSEQ)   // 4096
#define C3       (3 * N_EMBD)     // 3072

typedef unsigned short ushort_t;
typedef __attribute__((ext_vector_type(8))) short bf16x8;
typedef __attribute__((ext_vector_type(4))) float f32x4;

__device__ __forceinline__ float fake_quant(float x, float scale, float zp) {
    float q = rintf(x / scale + zp);
    q = fminf(fmaxf(q, 0.0f), 255.0f);
    return (q - zp) * scale;
}

__device__ __forceinline__ ushort_t bf16bits(float f) {
    union { __hip_bfloat16 h; ushort_t u; } c;
    c.h = __float2bfloat16(f);
    return c.u;
}

__device__ __forceinline__ float bfraw2f(ushort_t u) {
    union { unsigned int i; float f; } c; c.i = ((unsigned int)u) << 16; return c.f;
}

// ---------------- fused prep kernel (r7-proven) ----------------
#define NB_LORA 1024   // 256 x 4
#define NB_TRA  3072   // (C3/32) x (N_EMBD/32) = 96 x 32
#define NB_TRP  1024   // 32 x 32
#define NB_CVT  4096   // M*N/4/256

__device__ __forceinline__ void transpose_body(
        const float* __restrict__ in, __hip_bfloat16* __restrict__ hiT,
        __hip_bfloat16* __restrict__ loT, int R, int C,
        int c0, int r0, int tid, float* sh) {
    float (*tl)[33] = (float(*)[33])sh;
    const int tx = tid & 31, ty = tid >> 5;
    for (int i = ty; i < 32; i += 8)
        tl[i][tx] = in[(size_t)(r0 + i) * C + c0 + tx];
    __syncthreads();
    for (int i = ty; i < 32; i += 8) {
        float v = tl[tx][i];
        __hip_bfloat16 h = __float2bfloat16(v);
        size_t o = (size_t)(c0 + i) * R + r0 + tx;
        hiT[o] = h;
        if (loT) loT[o] = __float2bfloat16(v - __bfloat162float(h));
    }
}

__global__ __launch_bounds__(256)
void prep_kernel(const float* __restrict__ x,
                 const float* __restrict__ w_attn,
                 const float* __restrict__ w_proj,
                 const float* __restrict__ la_attn,
                 __hip_bfloat16* __restrict__ x_hi,
                 __hip_bfloat16* __restrict__ x_lo,
                 __hip_bfloat16* __restrict__ wqT_h,
                 __hip_bfloat16* __restrict__ wqT_l,
                 __hip_bfloat16* __restrict__ wpT,
                 float* __restrict__ t_attn_p) {
    __shared__ float sh[33 * 32];           // 4224B: transpose(32x33) / lora(16x64)
    const int tid = threadIdx.x;
    int b = blockIdx.x;

    if (b < NB_LORA) {                       // ---- lora_t_part (fp32 x) ----
        const int bx = b & 255, by = b >> 8;
        float (*Xs)[64] = (float(*)[64])sh;
        const int ty = tid >> 4, tx = tid & 15;
        const int row0 = bx * 16;
        const int kbase = by * 256;
        float acc = 0.0f;
        for (int k0 = kbase; k0 < kbase + 256; k0 += 64) {
            int rr = tid >> 4, kk = (tid & 15) * 4;
            float4 v = *(const float4*)(x + (size_t)(row0 + rr) * N_EMBD + k0 + kk);
            Xs[rr][kk] = v.x; Xs[rr][kk + 1] = v.y; Xs[rr][kk + 2] = v.z; Xs[rr][kk + 3] = v.w;
            __syncthreads();
            for (int k = 0; k < 64; ++k)
                acc += Xs[ty][k] * la_attn[(size_t)(k0 + k) * RANK + tx];
            __syncthreads();
        }
        t_attn_p[((size_t)by * M_TOTAL + row0 + ty) * RANK + tx] = acc;
        return;
    }
    b -= NB_LORA;
    if (b < NB_TRA) {                        // ---- transpose w_attn (hi+lo) ----
        const int gx = b % (C3 / 32), gy = b / (C3 / 32);
        transpose_body(w_attn, wqT_h, wqT_l, N_EMBD, C3, gx * 32, gy * 32, tid, sh);
        return;
    }
    b -= NB_TRA;
    if (b < NB_TRP) {                        // ---- transpose w_proj (hi only) ----
        const int gx = b & 31, gy = b >> 5;
        transpose_body(w_proj, wpT, nullptr, N_EMBD, N_EMBD, gx * 32, gy * 32, tid, sh);
        return;
    }
    b -= NB_TRP;
    {                                        // ---- cvt_split (exact fit) ----
        const int i = b * 256 + tid;
        float4 v = ((const float4*)x)[i];
        float vs[4] = {v.x, v.y, v.z, v.w};
        #pragma unroll
        for (int k = 0; k < 4; ++k) {
            __hip_bfloat16 h = __float2bfloat16(vs[k]);
            x_hi[i * 4 + k] = h;
            x_lo[i * 4 + k] = __float2bfloat16(vs[k] - __bfloat162float(h));
        }
    }
}

// Vb[bh][t][d] -> Vt[bh][d][t]  (bf16 transpose, 64x64 tiles)
__global__ void vtrans_kernel(const ushort_t* __restrict__ Vb,
                              ushort_t* __restrict__ Vt) {
    __shared__ ushort_t tl[64][68];
    const int bh = blockIdx.x & 31, tt = blockIdx.x >> 5;
    const int tid = threadIdx.x;
    {
        const int t = tid >> 2, d0 = (tid & 3) * 16;
        const uint4 u = *(const uint4*)(Vb + ((size_t)bh * TSEQ + tt * 64 + t) * 64 + d0);
        *(uint4*)&tl[t][d0] = u;
        *(uint4*)&tl[t][d0 + 8] = *(const uint4*)(Vb + ((size_t)bh * TSEQ + tt * 64 + t) * 64 + d0 + 8);
    }
    __syncthreads();
    const int d = tid >> 2, t0 = (tid & 3) * 16;
    unsigned int wbuf[8];
    #pragma unroll
    for (int j = 0; j < 8; ++j)
        wbuf[j] = (unsigned int)tl[t0 + 2 * j][d] | ((unsigned int)tl[t0 + 2 * j + 1][d] << 16);
    ushort_t* dst = Vt + ((size_t)bh * 64 + d) * TSEQ + tt * 64 + t0;
    *(uint4*)dst       = make_uint4(wbuf[0], wbuf[1], wbuf[2], wbuf[3]);
    *(uint4*)(dst + 8) = make_uint4(wbuf[4], wbuf[5], wbuf[6], wbuf[7]);
}

// ---------------- LoRA rank-16 projection on bf16 attn output ----------------
__global__ void lora_t_part_bf16_kernel(const ushort_t* __restrict__ x,
                                        const float* __restrict__ la,
                                        float* __restrict__ tpart, int K) {
    __shared__ float Xs[16][64];
    const int tid = threadIdx.x;
    const int ty = tid >> 4, tx = tid & 15;
    const int row0 = blockIdx.x * 16;
    const int kbase = blockIdx.y * 256;
    float acc = 0.0f;
    for (int k0 = kbase; k0 < kbase + 256; k0 += 64) {
        int rr = tid >> 4, kk = (tid & 15) * 4;
        const ushort4 u = *(const ushort4*)(x + (size_t)(row0 + rr) * K + k0 + kk);
        Xs[rr][kk] = bfraw2f(u.x); Xs[rr][kk + 1] = bfraw2f(u.y);
        Xs[rr][kk + 2] = bfraw2f(u.z); Xs[rr][kk + 3] = bfraw2f(u.w);
        __syncthreads();
        for (int k = 0; k < 64; ++k)
            acc += Xs[ty][k] * la[(size_t)(k0 + k) * RANK + tx];
        __syncthreads();
    }
    tpart[((size_t)blockIdx.y * M_TOTAL + row0 + ty) * RANK + tx] = acc;
}

// ---------------- MFMA GEMM (TMxTN tile, BK=32, 3-buf counted pipeline) ----------------
// r8-proven pipeline; r15 adds TN (tile cols). proj = <false,64,64>: 64x64
// tiles -> grid 16x64 = 1024 blocks = 4/CU (was 2/CU grid-limited; proj is
// latency-bound like QKV and TLP is the proven lever). A-panel re-reads
// double: irrelevant at 16% HBM (r2/r3 evidence). No launch_bounds min-wave
// hint (r9 lesson: VGPR squeeze -> scratch spill). QKV = <true,128,128>,
// byte-identical to the 298us anchor.
__device__ __forceinline__ int sw_off(int r, int c) {
    return ((r >> 1) << 7) + (((((r & 1) << 2) | c) ^ ((r >> 1) & 7)) << 4);
}

template <bool SPLIT, int TM, int TN>
__global__ __launch_bounds__(256, 3)
void gemm_mfma_kernel(const __hip_bfloat16* __restrict__ Ah,
                      const __hip_bfloat16* __restrict__ Al,
                      const __hip_bfloat16* __restrict__ Bh,
                      const __hip_bfloat16* __restrict__ Bl,
                      const float* __restrict__ bias,
                      const float* __restrict__ tpart,
                      const float* __restrict__ lb,
                      float* __restrict__ Cf,
                      ushort_t* __restrict__ Qb,
                      ushort_t* __restrict__ Kb,
                      ushort_t* __restrict__ Vb,
                      const float* __restrict__ sp,
                      const float* __restrict__ zp,
                      int M, int N, int K, int split_col0, int out_mode) {
    constexpr int TILEA = TM * 32;              // bf16 elements per A tile
    constexpr int TILEB = TN * 32;              // bf16 elements per B tile
    constexpr int MI = TM / 32;                 // acc row-frags per wave
    constexpr int NJ = TN / 32;                 // acc col-frags per wave
    constexpr int SLOADS = (TM == 128 ? 2 : 1) + (TN == 128 ? 2 : 1);
    __shared__ __align__(16) __hip_bfloat16 As[3 * TILEA];
    __shared__ __align__(16) __hip_bfloat16 Bs[3 * TILEB];
    float* Ts = (float*)As;                     // epilogue overlay (dead after K-loop)
    float* Ls = (float*)Bs;

    const int tid = threadIdx.x;
    const int lane = tid & 63, w = tid >> 6;

    // ---- block mapping ----
    int bcol, brow;
    {
        const int NC = gridDim.x, NR = gridDim.y;
        const int lid = blockIdx.y * NC + blockIdx.x;
        const int xcd = lid & 7, s = lid >> 3;
        const int cw = NC >> 1, rh = NR >> 2;
        const int cg = xcd & 1, rg = xcd >> 1;
        if (SPLIT) {
            bcol = 2 * (s % cw) + cg;             // even/odd column interleave
            brow = rg * rh + (s / cw);
        } else {
            bcol = cg * cw + (s % cw);
            brow = rg * rh + (s / cw);
        }
    }
    const int row0 = brow * TM, col0 = bcol * TN;
    const int wr = (w >> 1) * (TM >> 1), wc = (w & 1) * (TN >> 1);
    const bool do_split = SPLIT && (col0 >= split_col0);

    const int s_lc = (lane & 7) ^ ((lane >> 3) & 7);
    const int s_rb = 2 * (lane >> 3) + (s_lc >> 2);
    const int s_c8 = (s_lc & 3) * 8;

    float qsc = 0.f, qzp = 0.f;
    if (out_mode == 1) { qsc = sp[0]; qzp = zp[0]; }

    f32x4 acc[MI][NJ];
    #pragma unroll
    for (int i = 0; i < MI; ++i)
        #pragma unroll
        for (int j = 0; j < NJ; ++j)
            acc[i][j] = (f32x4){0.f, 0.f, 0.f, 0.f};

    const int arow = wr + (lane & 15);
    const int chunk = lane >> 4;

    // lo-operand global pointers (per-lane MFMA fragments, 16B each)
    const ushort_t* alp[MI];
    const ushort_t* blp[NJ];
    if (do_split) {
        #pragma unroll
        for (int mi = 0; mi < MI; ++mi)
            alp[mi] = (const ushort_t*)Al + (size_t)(row0 + arow + mi * 16) * K + chunk * 8;
        #pragma unroll
        for (int nj = 0; nj < NJ; ++nj)
            blp[nj] = (const ushort_t*)Bl + (size_t)(col0 + wc + nj * 16 + (lane & 15)) * K + chunk * 8;
    }

    auto stage = [&](int buf, int kidx) {
        const int k0 = kidx << 5;
        __hip_bfloat16* dA = As + buf * TILEA;
        __hip_bfloat16* dB = Bs + buf * TILEB;
        if (TM == 128) {
            #pragma unroll
            for (int qq = 0; qq < 2; ++qq) {
                const int q = 2 * w + qq;
                const int r = 16 * q + s_rb;
                const __hip_bfloat16* gA = Ah + (size_t)(row0 + r) * K + k0 + s_c8;
                __builtin_amdgcn_global_load_lds(
                    (const __attribute__((address_space(1))) void*)gA,
                    (__attribute__((address_space(3))) void*)(dA + q * 512), 16, 0, 0);
            }
        } else {
            const int rA = 16 * w + s_rb;        // 4 A-groups, one per wave
            const __hip_bfloat16* gA = Ah + (size_t)(row0 + rA) * K + k0 + s_c8;
            __builtin_amdgcn_global_load_lds(
                (const __attribute__((address_space(1))) void*)gA,
                (__attribute__((address_space(3))) void*)(dA + w * 512), 16, 0, 0);
        }
        if (TN == 128) {
            #pragma unroll
            for (int qq = 0; qq < 2; ++qq) {
                const int q = 2 * w + qq;
                const int r = 16 * q + s_rb;
                const __hip_bfloat16* gB = Bh + (size_t)(col0 + r) * K + k0 + s_c8;
                __builtin_amdgcn_global_load_lds(
                    (const __attribute__((address_space(1))) void*)gB,
                    (__attribute__((address_space(3))) void*)(dB + q * 512), 16, 0, 0);
            }
        } else {
            const int rB = 16 * w + s_rb;        // 4 B-groups, one per wave
            const __hip_bfloat16* gB = Bh + (size_t)(col0 + rB) * K + k0 + s_c8;
            __builtin_amdgcn_global_load_lds(
                (const __attribute__((address_space(1))) void*)gB,
                (__attribute__((address_space(3))) void*)(dB + w * 512), 16, 0, 0);
        }
    };

    const int KI = K >> 5;                       // K iterations (32 for K=1024)
    stage(0, 0);
    stage(1, 1);
    int bcur = 0, bstage = 2;
    for (int kk = 0; kk < KI; ++kk) {
        // tile kk ready after this wait; tile kk+1 stays in flight (never drain)
        if (kk == KI - 1) {
            asm volatile("s_waitcnt vmcnt(0)" ::: "memory");
        } else if (SLOADS == 4) {
            asm volatile("s_waitcnt vmcnt(4)" ::: "memory");
        } else if (SLOADS == 3) {
            asm volatile("s_waitcnt vmcnt(3)" ::: "memory");
        } else {
            asm volatile("s_waitcnt vmcnt(2)" ::: "memory");
        }
        __builtin_amdgcn_s_barrier();

        const int k0 = kk << 5;
        // lo reg loads FIRST (before stage), so their implicit wait never
        // requires draining the stage(t+2) prefetch issued below.
        bf16x8 a_l[MI], b_l[NJ];
        if (do_split) {
            #pragma unroll
            for (int mi = 0; mi < MI; ++mi) a_l[mi] = *(const bf16x8*)(alp[mi] + k0);
            #pragma unroll
            for (int nj = 0; nj < NJ; ++nj) b_l[nj] = *(const bf16x8*)(blp[nj] + k0);
        }
        if (kk + 2 < KI) { stage(bstage, kk + 2); bstage = (bstage == 2) ? 0 : bstage + 1; }

        const char* ab = (const char*)(As + bcur * TILEA);
        const char* bb = (const char*)(Bs + bcur * TILEB);
        bf16x8 a_h[MI], b_h[NJ];
        #pragma unroll
        for (int mi = 0; mi < MI; ++mi)
            a_h[mi] = *(const bf16x8*)(ab + sw_off(arow + mi * 16, chunk));
        #pragma unroll
        for (int nj = 0; nj < NJ; ++nj)
            b_h[nj] = *(const bf16x8*)(bb + sw_off(wc + nj * 16 + (lane & 15), chunk));
        // hi MFMAs first: cover before the lo-reg wait lands
        #pragma unroll
        for (int mi = 0; mi < MI; ++mi)
            #pragma unroll
            for (int nj = 0; nj < NJ; ++nj)
                acc[mi][nj] = __builtin_amdgcn_mfma_f32_16x16x32_bf16(a_h[mi], b_h[nj], acc[mi][nj], 0, 0, 0);
        if (do_split) {
            #pragma unroll
            for (int mi = 0; mi < MI; ++mi)
                #pragma unroll
                for (int nj = 0; nj < NJ; ++nj) {
                    acc[mi][nj] = __builtin_amdgcn_mfma_f32_16x16x32_bf16(a_h[mi], b_l[nj], acc[mi][nj], 0, 0, 0);
                    acc[mi][nj] = __builtin_amdgcn_mfma_f32_16x16x32_bf16(a_l[mi], b_h[nj], acc[mi][nj], 0, 0, 0);
                }
        }
        bcur = (bcur == 2) ? 0 : bcur + 1;
    }
    __syncthreads();   // all compute reads done before Ts/Ls overlay writes

    // ---- epilogue: bias + LORA_SCALE * ((sum of tparts) @ lb) ----
    {
        int r = tid >> 1, j0 = (tid & 1) * 8;
        if (r < TM) {
            float4 t0 = {0, 0, 0, 0}, t1 = {0, 0, 0, 0};
            #pragma unroll
            for (int c = 0; c < 4; ++c) {
                const float* src = tpart + ((size_t)c * M_TOTAL + row0 + r) * RANK + j0;
                float4 s0 = *(const float4*)src;
                float4 s1 = *(const float4*)(src + 4);
                t0.x += s0.x; t0.y += s0.y; t0.z += s0.z; t0.w += s0.w;
                t1.x += s1.x; t1.y += s1.y; t1.z += s1.z; t1.w += s1.w;
            }
            *(float4*)(Ts + r * 16 + j0)     = t0;
            *(float4*)(Ts + r * 16 + j0 + 4) = t1;
        }
        if (TN == 128) {
            int rr = tid >> 4, c0 = (tid & 15) * 8;
            const float4* lsrc = (const float4*)(lb + (size_t)rr * N + col0 + c0);
            float4* ldst = (float4*)(Ls + rr * TN + c0);
            ldst[0] = lsrc[0]; ldst[1] = lsrc[1];
        } else {
            int rr = tid >> 4, c0 = (tid & 15) * 4;
            *(float4*)(Ls + rr * TN + c0) =
                *(const float4*)(lb + (size_t)rr * N + col0 + c0);
        }
    }
    __syncthreads();
    #pragma unroll
    for (int mi = 0; mi < MI; ++mi)
        #pragma unroll
        for (int nj = 0; nj < NJ; ++nj) {
            const int coll = wc + nj * 16 + (lane & 15);
            const float bv = bias[col0 + coll];
            #pragma unroll
            for (int rg = 0; rg < 4; ++rg) {
                const int rowl = wr + mi * 16 + (lane >> 4) * 4 + rg;
                float lsum = 0.f;
                #pragma unroll
                for (int rr = 0; rr < 16; ++rr)
                    lsum += Ts[rowl * 16 + rr] * Ls[rr * TN + coll];
                const float val = acc[mi][nj][rg] + bv + LORA_SCALE * lsum;
                if (out_mode == 0) {
                    Cf[(size_t)(row0 + rowl) * N + col0 + coll] = val;
                } else {
                    const int R = row0 + rowl;
                    const int b = R >> 11, t = R & 2047;
                    const int CN = col0 + coll;
                    const int sec = CN >> 10, head = (CN >> 6) & 15, d = CN & 63;
                    const size_t off = (((size_t)(b * 16 + head)) * TSEQ + t) * 64 + d;
                    if (sec == 0)      Qb[off] = bf16bits(val * 0.125f);
                    else if (sec == 1) Kb[off] = bf16bits(fake_quant(val, qsc, qzp));
                    else               Vb[off] = bf16bits(fake_quant(val, qsc, qzp));
                }
            }
        }
}

// ---------------- MFMA flash attention (counted-vmcnt 2-buf pipeline) ----------------
// r10-proven body + r14 boustrophedon qt map (measured neutral, kept).
__global__ __launch_bounds__(256)
void mfma_attn_kernel(const ushort_t* __restrict__ Qb,   // [bh][T][64] (x0.125)
                      const ushort_t* __restrict__ Kq,   // [bh][T][64]
                      const ushort_t* __restrict__ Vtq,  // [bh][64][T]
                      ushort_t* __restrict__ outb) {     // [B][T][1024] bf16
    const int bx = blockIdx.x;
    const int bh = bx & 31;
    const int g = (bx >> 5) & 7, band = bx >> 8;
    const int qt = (band == 0) ? 31 - g
                 : (band == 1) ? 16 + g
                 : (band == 2) ? 15 - g
                 :               g;
    const int b = bh >> 4, h = bh & 15;
    const int tid = threadIdx.x;
    const int lane = tid & 63, w = tid >> 6;
    const int m16 = lane & 15, qc = lane >> 4;
    const int m7 = m16 & 7;

    __shared__ ushort_t Ks[2][4096];
    __shared__ ushort_t Vs[2][4096];
    __shared__ ushort_t Ps[4096];

    const int s_g = (lane & 7) ^ ((lane >> 3) & 7);
    const int s_r = lane >> 3;

    const ushort_t* Qg = Qb + (size_t)bh * TSEQ * 64;
    const ushort_t* Kg = Kq + (size_t)bh * TSEQ * 64;
    const ushort_t* Vg = Vtq + (size_t)bh * 64 * TSEQ;

    auto stageKV = [&](int buf, int kt) {
        #pragma unroll
        for (int pp = 0; pp < 2; ++pp) {
            const int p = 2 * w + pp;
            const ushort_t* gk = Kg + ((size_t)(kt * 64 + 8 * p + s_r)) * 64 + s_g * 8;
            __builtin_amdgcn_global_load_lds(
                (const __attribute__((address_space(1))) void*)gk,
                (__attribute__((address_space(3))) void*)(Ks[buf] + p * 512), 16, 0, 0);
            const ushort_t* gv = Vg + ((size_t)(8 * p + s_r)) * TSEQ + kt * 64 + s_g * 8;
            __builtin_amdgcn_global_load_lds(
                (const __attribute__((address_space(1))) void*)gv,
                (__attribute__((address_space(3))) void*)(Vs[buf] + p * 512), 16, 0, 0);
        }
    };

    stageKV(0, 0);

    // Q fragment straight from global: Q[qt*64 + 16w + m16][(qc+4c)*8 .. +7]
    bf16x8 a_q[2];
    {
        const ushort_t* qrow = Qg + (size_t)(qt * 64 + 16 * w + m16) * 64;
        a_q[0] = *(const bf16x8*)(qrow + qc * 8);
        a_q[1] = *(const bf16x8*)(qrow + (qc + 4) * 8);
    }

    float m_st[4], l_st[4];
    f32x4 o_acc[4];
    #pragma unroll
    for (int r = 0; r < 4; ++r) { m_st[r] = -INFINITY; l_st[r] = 0.0f; }
    #pragma unroll
    for (int dj = 0; dj < 4; ++dj) o_acc[dj] = (f32x4){0.f, 0.f, 0.f, 0.f};

    for (int kt = 0; kt <= qt; ++kt) {
        const int cur = kt & 1;
        if (kt < qt) {
            stageKV(cur ^ 1, kt + 1);
            asm volatile("s_waitcnt vmcnt(4)" ::: "memory");   // stage(kt) done; prefetch in flight
        } else {
            asm volatile("s_waitcnt vmcnt(0)" ::: "memory");   // last tile: drain stage(qt)
        }
        __builtin_amdgcn_s_barrier();   // B1: Ks/Vs[cur] fully written

        const bool diag = (kt == qt);
        const int nj_hi = diag ? (w + 1) : 4;

        f32x4 s[4];
        #pragma unroll
        for (int nj = 0; nj < 4; ++nj) s[nj] = (f32x4){0.f, 0.f, 0.f, 0.f};
        #pragma unroll
        for (int c = 0; c < 2; ++c) {
            #pragma unroll
            for (int nj = 0; nj < 4; ++nj) {
                if (nj < nj_hi) {
                    const int row = 16 * nj + m16;
                    const int gg = qc + 4 * c;
                    bf16x8 bk = *(const bf16x8*)((const char*)Ks[cur] + row * 128 + ((gg ^ m7) << 4));
                    s[nj] = __builtin_amdgcn_mfma_f32_16x16x32_bf16(a_q[c], bk, s[nj], 0, 0, 0);
                }
            }
        }

        float alpha[4], p_[4][4];
        #pragma unroll
        for (int reg = 0; reg < 4; ++reg) {
            const int qrow = 16 * w + 4 * qc + reg;
            float sv[4];
            float rm = -INFINITY;
            #pragma unroll
            for (int nj = 0; nj < 4; ++nj) {
                float v = s[nj][reg];
                if (diag && (m16 + 16 * nj > qrow)) v = -INFINITY;
                sv[nj] = v;
                rm = fmaxf(rm, v);
            }
            #pragma unroll
            for (int off = 1; off < 16; off <<= 1)
                rm = fmaxf(rm, __shfl_xor(rm, off, 16));
            const float mo = m_st[reg];
            const float mn = fmaxf(mo, rm);
            const float al = __expf(mo - mn);
            float rs = 0.f;
            #pragma unroll
            for (int nj = 0; nj < 4; ++nj) {
                float pv = __expf(sv[nj] - mn);
                p_[reg][nj] = pv;
                rs += pv;
            }
            #pragma unroll
            for (int off = 1; off < 16; off <<= 1)
                rs += __shfl_xor(rs, off, 16);
            l_st[reg] = al * l_st[reg] + rs;
            m_st[reg] = mn;
            alpha[reg] = al;
        }

        #pragma unroll
        for (int reg = 0; reg < 4; ++reg) {
            const int row = 16 * w + 4 * qc + reg;
            const int r7 = row & 7;
            #pragma unroll
            for (int nj = 0; nj < 4; ++nj) {
                const int k = m16 + 16 * nj;
                Ps[row * 64 + (((k >> 3) ^ r7) << 3) + (k & 7)] = bf16bits(p_[reg][nj]);
            }
        }

        #pragma unroll
        for (int dj = 0; dj < 4; ++dj)
            #pragma unroll
            for (int reg = 0; reg < 4; ++reg)
                o_acc[dj][reg] *= alpha[reg];

        const int c_hi = diag ? (w >= 2 ? 2 : 1) : 2;
        #pragma unroll
        for (int c = 0; c < 2; ++c) {
            if (c < c_hi) {
                const int rowp = 16 * w + m16;
                const int gg = qc + 4 * c;
                bf16x8 ap = *(const bf16x8*)((const char*)Ps + rowp * 128 + ((gg ^ m7) << 4));
                #pragma unroll
                for (int dj = 0; dj < 4; ++dj) {
                    const int rowv = 16 * dj + m16;
                    bf16x8 bv = *(const bf16x8*)((const char*)Vs[cur] + rowv * 128 + ((gg ^ m7) << 4));
                    o_acc[dj] = __builtin_amdgcn_mfma_f32_16x16x32_bf16(ap, bv, o_acc[dj], 0, 0, 0);
                }
            }
        }
        asm volatile("s_barrier" ::: "memory");   // B2: all waves done with buf[cur]
    }

    #pragma unroll
    for (int reg = 0; reg < 4; ++reg) {
        const float inv = 1.0f / l_st[reg];
        const int q = qt * 64 + 16 * w + 4 * qc + reg;
        #pragma unroll
        for (int dj = 0; dj < 4; ++dj) {
            const int d = m16 + 16 * dj;
            outb[((size_t)b * TSEQ + q) * N_EMBD + h * 64 + d] = bf16bits(o_acc[dj][reg] * inv);
        }
    }
}

extern "C" void kernel_launch(void* const* d_in, const int* in_sizes, int n_in,
                              void* d_out, int out_size, void* d_ws, size_t ws_size,
                              hipStream_t stream) {
    const float* x        = (const float*)d_in[0];
    const float* w_attn   = (const float*)d_in[1];
    const float* b_attn   = (const float*)d_in[2];
    const float* la_attn  = (const float*)d_in[3];
    const float* lb_attn  = (const float*)d_in[4];
    const float* w_proj   = (const float*)d_in[5];
    const float* b_proj   = (const float*)d_in[6];
    const float* la_proj  = (const float*)d_in[7];
    const float* lb_proj  = (const float*)d_in[8];
    const float* kv_scale = (const float*)d_in[9];
    const float* kv_zp    = (const float*)d_in[10];
    float* out = (float*)d_out;

    char* ws = (char*)d_ws;
    float* t_attn_p       = (float*)ws;          ws += (size_t)4 * M_TOTAL * RANK * 4;
    float* t_proj_p       = (float*)ws;          ws += (size_t)4 * M_TOTAL * RANK * 4;
    ushort_t* aob         = (ushort_t*)ws;       ws += (size_t)M_TOTAL * N_EMBD * 2;
    __hip_bfloat16* x_hi  = (__hip_bfloat16*)ws; ws += (size_t)M_TOTAL * N_EMBD * 2;
    __hip_bfloat16* x_lo  = (__hip_bfloat16*)ws; ws += (size_t)M_TOTAL * N_EMBD * 2;
    __hip_bfloat16* wqT_h = (__hip_bfloat16*)ws; ws += (size_t)C3 * N_EMBD * 2;
    __hip_bfloat16* wqT_l = (__hip_bfloat16*)ws; ws += (size_t)C3 * N_EMBD * 2;
    __hip_bfloat16* wpT   = (__hip_bfloat16*)ws; ws += (size_t)N_EMBD * N_EMBD * 2;
    ushort_t* Qb          = (ushort_t*)ws;       ws += (size_t)32 * TSEQ * 64 * 2;
    ushort_t* Kb          = (ushort_t*)ws;       ws += (size_t)32 * TSEQ * 64 * 2;
    ushort_t* Vb          = (ushort_t*)ws;       ws += (size_t)32 * TSEQ * 64 * 2;
    ushort_t* Vtq         = (ushort_t*)ws;       ws += (size_t)32 * 64 * TSEQ * 2;

    // fused prep: lora + transpose(w_attn) + transpose(w_proj) + cvt_split
    prep_kernel<<<dim3(NB_LORA + NB_TRA + NB_TRP + NB_CVT), 256, 0, stream>>>(
        x, w_attn, w_proj, la_attn,
        x_hi, x_lo, wqT_h, wqT_l, wpT, t_attn_p);

    // QKV: split only V columns (col0 >= 2048); 128x128 tiles, balanced map.
    gemm_mfma_kernel<true, 128, 128><<<dim3(24, 32), 256, 0, stream>>>(
        x_hi, x_lo, wqT_h, wqT_l, b_attn, t_attn_p, lb_attn,
        nullptr, Qb, Kb, Vb, kv_scale, kv_zp,
        M_TOTAL, C3, N_EMBD, 2 * N_EMBD, 1);

    vtrans_kernel<<<dim3(32 * (TSEQ / 64)), 256, 0, stream>>>(Vb, Vtq);

    mfma_attn_kernel<<<dim3(32 * 32), 256, 0, stream>>>(Qb, Kb, Vtq, aob);

    lora_t_part_bf16_kernel<<<dim3(M_TOTAL / 16, 4), 256, 0, stream>>>(aob, la_proj, t_proj_p, N_EMBD);

    // proj: 64x64 tiles -> grid 16x64 = 1024 blocks = 4/CU (TLP lever)
    gemm_mfma_kernel<false, 64, 64><<<dim3(16, 64), 256, 0, stream>>>(
        (const __hip_bfloat16*)aob, nullptr, wpT, nullptr, b_proj, t_proj_p, lb_proj,
        out, nullptr, nullptr, nullptr, nullptr, nullptr,
        M_TOTAL, N_EMBD, N_EMBD, 1 << 30, 0);
}

// Round 17
// 296.742 us; speedup vs baseline: 1.0375x; 1.0375x over previous
//
#include <hip/hip_runtime.h>
#include <hip/hip_bf16.h>
#include <math.h>

#define N_EMBD   1024
#define N_HEAD   16
#define HEAD_DIM 64
#define BATCH    2
#define TSEQ     2048
#define RANK     16
#define LORA_SCALE 2.0f
#define M_TOTAL  (BATCH * TSEQ)   // 4096
#define C3       (3 * N_EMBD)     // 3072

typedef unsigned short ushort_t;
typedef __attribute__((ext_vector_type(8))) short bf16x8;
typedef __attribute__((ext_vector_type(4))) float f32x4;

__device__ __forceinline__ float fake_quant(float x, float scale, float zp) {
    float q = rintf(x / scale + zp);
    q = fminf(fmaxf(q, 0.0f), 255.0f);
    return (q - zp) * scale;
}

__device__ __forceinline__ ushort_t bf16bits(float f) {
    union { __hip_bfloat16 h; ushort_t u; } c;
    c.h = __float2bfloat16(f);
    return c.u;
}

__device__ __forceinline__ float bfraw2f(ushort_t u) {
    union { unsigned int i; float f; } c; c.i = ((unsigned int)u) << 16; return c.f;
}

// ---------------- fused prep kernel (r7-proven) ----------------
#define NB_LORA 1024   // 256 x 4
#define NB_TRA  3072   // (C3/32) x (N_EMBD/32) = 96 x 32
#define NB_TRP  1024   // 32 x 32
#define NB_CVT  4096   // M*N/4/256

__device__ __forceinline__ void transpose_body(
        const float* __restrict__ in, __hip_bfloat16* __restrict__ hiT,
        __hip_bfloat16* __restrict__ loT, int R, int C,
        int c0, int r0, int tid, float* sh) {
    float (*tl)[33] = (float(*)[33])sh;
    const int tx = tid & 31, ty = tid >> 5;
    for (int i = ty; i < 32; i += 8)
        tl[i][tx] = in[(size_t)(r0 + i) * C + c0 + tx];
    __syncthreads();
    for (int i = ty; i < 32; i += 8) {
        float v = tl[tx][i];
        __hip_bfloat16 h = __float2bfloat16(v);
        size_t o = (size_t)(c0 + i) * R + r0 + tx;
        hiT[o] = h;
        if (loT) loT[o] = __float2bfloat16(v - __bfloat162float(h));
    }
}

__global__ __launch_bounds__(256)
void prep_kernel(const float* __restrict__ x,
                 const float* __restrict__ w_attn,
                 const float* __restrict__ w_proj,
                 const float* __restrict__ la_attn,
                 __hip_bfloat16* __restrict__ x_hi,
                 __hip_bfloat16* __restrict__ x_lo,
                 __hip_bfloat16* __restrict__ wqT_h,
                 __hip_bfloat16* __restrict__ wqT_l,
                 __hip_bfloat16* __restrict__ wpT,
                 float* __restrict__ t_attn_p) {
    __shared__ float sh[33 * 32];           // 4224B: transpose(32x33) / lora(16x64)
    const int tid = threadIdx.x;
    int b = blockIdx.x;

    if (b < NB_LORA) {                       // ---- lora_t_part (fp32 x) ----
        const int bx = b & 255, by = b >> 8;
        float (*Xs)[64] = (float(*)[64])sh;
        const int ty = tid >> 4, tx = tid & 15;
        const int row0 = bx * 16;
        const int kbase = by * 256;
        float acc = 0.0f;
        for (int k0 = kbase; k0 < kbase + 256; k0 += 64) {
            int rr = tid >> 4, kk = (tid & 15) * 4;
            float4 v = *(const float4*)(x + (size_t)(row0 + rr) * N_EMBD + k0 + kk);
            Xs[rr][kk] = v.x; Xs[rr][kk + 1] = v.y; Xs[rr][kk + 2] = v.z; Xs[rr][kk + 3] = v.w;
            __syncthreads();
            for (int k = 0; k < 64; ++k)
                acc += Xs[ty][k] * la_attn[(size_t)(k0 + k) * RANK + tx];
            __syncthreads();
        }
        t_attn_p[((size_t)by * M_TOTAL + row0 + ty) * RANK + tx] = acc;
        return;
    }
    b -= NB_LORA;
    if (b < NB_TRA) {                        // ---- transpose w_attn (hi+lo) ----
        const int gx = b % (C3 / 32), gy = b / (C3 / 32);
        transpose_body(w_attn, wqT_h, wqT_l, N_EMBD, C3, gx * 32, gy * 32, tid, sh);
        return;
    }
    b -= NB_TRA;
    if (b < NB_TRP) {                        // ---- transpose w_proj (hi only) ----
        const int gx = b & 31, gy = b >> 5;
        transpose_body(w_proj, wpT, nullptr, N_EMBD, N_EMBD, gx * 32, gy * 32, tid, sh);
        return;
    }
    b -= NB_TRP;
    {                                        // ---- cvt_split (exact fit) ----
        const int i = b * 256 + tid;
        float4 v = ((const float4*)x)[i];
        float vs[4] = {v.x, v.y, v.z, v.w};
        #pragma unroll
        for (int k = 0; k < 4; ++k) {
            __hip_bfloat16 h = __float2bfloat16(vs[k]);
            x_hi[i * 4 + k] = h;
            x_lo[i * 4 + k] = __float2bfloat16(vs[k] - __bfloat162float(h));
        }
    }
}

// Vb[bh][t][d] -> Vt[bh][d][t]  (bf16 transpose, 64x64 tiles)
__global__ void vtrans_kernel(const ushort_t* __restrict__ Vb,
                              ushort_t* __restrict__ Vt) {
    __shared__ ushort_t tl[64][68];
    const int bh = blockIdx.x & 31, tt = blockIdx.x >> 5;
    const int tid = threadIdx.x;
    {
        const int t = tid >> 2, d0 = (tid & 3) * 16;
        const uint4 u = *(const uint4*)(Vb + ((size_t)bh * TSEQ + tt * 64 + t) * 64 + d0);
        *(uint4*)&tl[t][d0] = u;
        *(uint4*)&tl[t][d0 + 8] = *(const uint4*)(Vb + ((size_t)bh * TSEQ + tt * 64 + t) * 64 + d0 + 8);
    }
    __syncthreads();
    const int d = tid >> 2, t0 = (tid & 3) * 16;
    unsigned int wbuf[8];
    #pragma unroll
    for (int j = 0; j < 8; ++j)
        wbuf[j] = (unsigned int)tl[t0 + 2 * j][d] | ((unsigned int)tl[t0 + 2 * j + 1][d] << 16);
    ushort_t* dst = Vt + ((size_t)bh * 64 + d) * TSEQ + tt * 64 + t0;
    *(uint4*)dst       = make_uint4(wbuf[0], wbuf[1], wbuf[2], wbuf[3]);
    *(uint4*)(dst + 8) = make_uint4(wbuf[4], wbuf[5], wbuf[6], wbuf[7]);
}

// ---------------- LoRA rank-16 projection on bf16 attn output ----------------
__global__ void lora_t_part_bf16_kernel(const ushort_t* __restrict__ x,
                                        const float* __restrict__ la,
                                        float* __restrict__ tpart, int K) {
    __shared__ float Xs[16][64];
    const int tid = threadIdx.x;
    const int ty = tid >> 4, tx = tid & 15;
    const int row0 = blockIdx.x * 16;
    const int kbase = blockIdx.y * 256;
    float acc = 0.0f;
    for (int k0 = kbase; k0 < kbase + 256; k0 += 64) {
        int rr = tid >> 4, kk = (tid & 15) * 4;
        const ushort4 u = *(const ushort4*)(x + (size_t)(row0 + rr) * K + k0 + kk);
        Xs[rr][kk] = bfraw2f(u.x); Xs[rr][kk + 1] = bfraw2f(u.y);
        Xs[rr][kk + 2] = bfraw2f(u.z); Xs[rr][kk + 3] = bfraw2f(u.w);
        __syncthreads();
        for (int k = 0; k < 64; ++k)
            acc += Xs[ty][k] * la[(size_t)(k0 + k) * RANK + tx];
        __syncthreads();
    }
    tpart[((size_t)blockIdx.y * M_TOTAL + row0 + ty) * RANK + tx] = acc;
}

// ---------------- MFMA GEMM (TMxTN tile, BK=32, 3-buf counted pipeline) ----------------
// r8-proven pipeline. Tile rules (r9/r15 evidence): QKV = 128x128; proj =
// 64x128 (TM=64 only where grid-limited). TN=64 regressed (+10us, r15): 4
// MFMAs/K-step can't amortize barrier+stage overhead even at 2x TLP. No
// launch_bounds min-wave hint (r9: VGPR squeeze -> scratch spill).
__device__ __forceinline__ int sw_off(int r, int c) {
    return ((r >> 1) << 7) + (((((r & 1) << 2) | c) ^ ((r >> 1) & 7)) << 4);
}

template <bool SPLIT, int TM, int TN>
__global__ __launch_bounds__(256, 3)
void gemm_mfma_kernel(const __hip_bfloat16* __restrict__ Ah,
                      const __hip_bfloat16* __restrict__ Al,
                      const __hip_bfloat16* __restrict__ Bh,
                      const __hip_bfloat16* __restrict__ Bl,
                      const float* __restrict__ bias,
                      const float* __restrict__ tpart,
                      const float* __restrict__ lb,
                      float* __restrict__ Cf,
                      ushort_t* __restrict__ Qb,
                      ushort_t* __restrict__ Kb,
                      ushort_t* __restrict__ Vb,
                      const float* __restrict__ sp,
                      const float* __restrict__ zp,
                      int M, int N, int K, int split_col0, int out_mode) {
    constexpr int TILEA = TM * 32;              // bf16 elements per A tile
    constexpr int TILEB = TN * 32;              // bf16 elements per B tile
    constexpr int MI = TM / 32;                 // acc row-frags per wave
    constexpr int NJ = TN / 32;                 // acc col-frags per wave
    constexpr int SLOADS = (TM == 128 ? 2 : 1) + (TN == 128 ? 2 : 1);
    __shared__ __align__(16) __hip_bfloat16 As[3 * TILEA];
    __shared__ __align__(16) __hip_bfloat16 Bs[3 * TILEB];
    float* Ts = (float*)As;                     // epilogue overlay (dead after K-loop)
    float* Ls = (float*)Bs;

    const int tid = threadIdx.x;
    const int lane = tid & 63, w = tid >> 6;

    // ---- block mapping ----
    int bcol, brow;
    {
        const int NC = gridDim.x, NR = gridDim.y;
        const int lid = blockIdx.y * NC + blockIdx.x;
        const int xcd = lid & 7, s = lid >> 3;
        const int cw = NC >> 1, rh = NR >> 2;
        const int cg = xcd & 1, rg = xcd >> 1;
        if (SPLIT) {
            bcol = 2 * (s % cw) + cg;             // even/odd column interleave
            brow = rg * rh + (s / cw);
        } else {
            bcol = cg * cw + (s % cw);
            brow = rg * rh + (s / cw);
        }
    }
    const int row0 = brow * TM, col0 = bcol * TN;
    const int wr = (w >> 1) * (TM >> 1), wc = (w & 1) * (TN >> 1);
    const bool do_split = SPLIT && (col0 >= split_col0);

    const int s_lc = (lane & 7) ^ ((lane >> 3) & 7);
    const int s_rb = 2 * (lane >> 3) + (s_lc >> 2);
    const int s_c8 = (s_lc & 3) * 8;

    float qsc = 0.f, qzp = 0.f;
    if (out_mode == 1) { qsc = sp[0]; qzp = zp[0]; }

    f32x4 acc[MI][NJ];
    #pragma unroll
    for (int i = 0; i < MI; ++i)
        #pragma unroll
        for (int j = 0; j < NJ; ++j)
            acc[i][j] = (f32x4){0.f, 0.f, 0.f, 0.f};

    const int arow = wr + (lane & 15);
    const int chunk = lane >> 4;

    // lo-operand global pointers (per-lane MFMA fragments, 16B each)
    const ushort_t* alp[MI];
    const ushort_t* blp[NJ];
    if (do_split) {
        #pragma unroll
        for (int mi = 0; mi < MI; ++mi)
            alp[mi] = (const ushort_t*)Al + (size_t)(row0 + arow + mi * 16) * K + chunk * 8;
        #pragma unroll
        for (int nj = 0; nj < NJ; ++nj)
            blp[nj] = (const ushort_t*)Bl + (size_t)(col0 + wc + nj * 16 + (lane & 15)) * K + chunk * 8;
    }

    auto stage = [&](int buf, int kidx) {
        const int k0 = kidx << 5;
        __hip_bfloat16* dA = As + buf * TILEA;
        __hip_bfloat16* dB = Bs + buf * TILEB;
        if (TM == 128) {
            #pragma unroll
            for (int qq = 0; qq < 2; ++qq) {
                const int q = 2 * w + qq;
                const int r = 16 * q + s_rb;
                const __hip_bfloat16* gA = Ah + (size_t)(row0 + r) * K + k0 + s_c8;
                __builtin_amdgcn_global_load_lds(
                    (const __attribute__((address_space(1))) void*)gA,
                    (__attribute__((address_space(3))) void*)(dA + q * 512), 16, 0, 0);
            }
        } else {
            const int rA = 16 * w + s_rb;        // 4 A-groups, one per wave
            const __hip_bfloat16* gA = Ah + (size_t)(row0 + rA) * K + k0 + s_c8;
            __builtin_amdgcn_global_load_lds(
                (const __attribute__((address_space(1))) void*)gA,
                (__attribute__((address_space(3))) void*)(dA + w * 512), 16, 0, 0);
        }
        if (TN == 128) {
            #pragma unroll
            for (int qq = 0; qq < 2; ++qq) {
                const int q = 2 * w + qq;
                const int r = 16 * q + s_rb;
                const __hip_bfloat16* gB = Bh + (size_t)(col0 + r) * K + k0 + s_c8;
                __builtin_amdgcn_global_load_lds(
                    (const __attribute__((address_space(1))) void*)gB,
                    (__attribute__((address_space(3))) void*)(dB + q * 512), 16, 0, 0);
            }
        } else {
            const int rB = 16 * w + s_rb;        // 4 B-groups, one per wave
            const __hip_bfloat16* gB = Bh + (size_t)(col0 + rB) * K + k0 + s_c8;
            __builtin_amdgcn_global_load_lds(
                (const __attribute__((address_space(1))) void*)gB,
                (__attribute__((address_space(3))) void*)(dB + w * 512), 16, 0, 0);
        }
    };

    const int KI = K >> 5;                       // K iterations (32 for K=1024)
    stage(0, 0);
    stage(1, 1);
    int bcur = 0, bstage = 2;
    for (int kk = 0; kk < KI; ++kk) {
        // tile kk ready after this wait; tile kk+1 stays in flight (never drain)
        if (kk == KI - 1) {
            asm volatile("s_waitcnt vmcnt(0)" ::: "memory");
        } else if (SLOADS == 4) {
            asm volatile("s_waitcnt vmcnt(4)" ::: "memory");
        } else if (SLOADS == 3) {
            asm volatile("s_waitcnt vmcnt(3)" ::: "memory");
        } else {
            asm volatile("s_waitcnt vmcnt(2)" ::: "memory");
        }
        __builtin_amdgcn_s_barrier();

        const int k0 = kk << 5;
        // lo reg loads FIRST (before stage), so their implicit wait never
        // requires draining the stage(t+2) prefetch issued below.
        bf16x8 a_l[MI], b_l[NJ];
        if (do_split) {
            #pragma unroll
            for (int mi = 0; mi < MI; ++mi) a_l[mi] = *(const bf16x8*)(alp[mi] + k0);
            #pragma unroll
            for (int nj = 0; nj < NJ; ++nj) b_l[nj] = *(const bf16x8*)(blp[nj] + k0);
        }
        if (kk + 2 < KI) { stage(bstage, kk + 2); bstage = (bstage == 2) ? 0 : bstage + 1; }

        const char* ab = (const char*)(As + bcur * TILEA);
        const char* bb = (const char*)(Bs + bcur * TILEB);
        bf16x8 a_h[MI], b_h[NJ];
        #pragma unroll
        for (int mi = 0; mi < MI; ++mi)
            a_h[mi] = *(const bf16x8*)(ab + sw_off(arow + mi * 16, chunk));
        #pragma unroll
        for (int nj = 0; nj < NJ; ++nj)
            b_h[nj] = *(const bf16x8*)(bb + sw_off(wc + nj * 16 + (lane & 15), chunk));
        // hi MFMAs first: cover before the lo-reg wait lands
        #pragma unroll
        for (int mi = 0; mi < MI; ++mi)
            #pragma unroll
            for (int nj = 0; nj < NJ; ++nj)
                acc[mi][nj] = __builtin_amdgcn_mfma_f32_16x16x32_bf16(a_h[mi], b_h[nj], acc[mi][nj], 0, 0, 0);
        if (do_split) {
            #pragma unroll
            for (int mi = 0; mi < MI; ++mi)
                #pragma unroll
                for (int nj = 0; nj < NJ; ++nj) {
                    acc[mi][nj] = __builtin_amdgcn_mfma_f32_16x16x32_bf16(a_h[mi], b_l[nj], acc[mi][nj], 0, 0, 0);
                    acc[mi][nj] = __builtin_amdgcn_mfma_f32_16x16x32_bf16(a_l[mi], b_h[nj], acc[mi][nj], 0, 0, 0);
                }
        }
        bcur = (bcur == 2) ? 0 : bcur + 1;
    }
    __syncthreads();   // all compute reads done before Ts/Ls overlay writes

    // ---- epilogue: bias + LORA_SCALE * ((sum of tparts) @ lb) ----
    {
        int r = tid >> 1, j0 = (tid & 1) * 8;
        if (r < TM) {
            float4 t0 = {0, 0, 0, 0}, t1 = {0, 0, 0, 0};
            #pragma unroll
            for (int c = 0; c < 4; ++c) {
                const float* src = tpart + ((size_t)c * M_TOTAL + row0 + r) * RANK + j0;
                float4 s0 = *(const float4*)src;
                float4 s1 = *(const float4*)(src + 4);
                t0.x += s0.x; t0.y += s0.y; t0.z += s0.z; t0.w += s0.w;
                t1.x += s1.x; t1.y += s1.y; t1.z += s1.z; t1.w += s1.w;
            }
            *(float4*)(Ts + r * 16 + j0)     = t0;
            *(float4*)(Ts + r * 16 + j0 + 4) = t1;
        }
        if (TN == 128) {
            int rr = tid >> 4, c0 = (tid & 15) * 8;
            const float4* lsrc = (const float4*)(lb + (size_t)rr * N + col0 + c0);
            float4* ldst = (float4*)(Ls + rr * TN + c0);
            ldst[0] = lsrc[0]; ldst[1] = lsrc[1];
        } else {
            int rr = tid >> 4, c0 = (tid & 15) * 4;
            *(float4*)(Ls + rr * TN + c0) =
                *(const float4*)(lb + (size_t)rr * N + col0 + c0);
        }
    }
    __syncthreads();
    #pragma unroll
    for (int mi = 0; mi < MI; ++mi)
        #pragma unroll
        for (int nj = 0; nj < NJ; ++nj) {
            const int coll = wc + nj * 16 + (lane & 15);
            const float bv = bias[col0 + coll];
            #pragma unroll
            for (int rg = 0; rg < 4; ++rg) {
                const int rowl = wr + mi * 16 + (lane >> 4) * 4 + rg;
                float lsum = 0.f;
                #pragma unroll
                for (int rr = 0; rr < 16; ++rr)
                    lsum += Ts[rowl * 16 + rr] * Ls[rr * TN + coll];
                const float val = acc[mi][nj][rg] + bv + LORA_SCALE * lsum;
                if (out_mode == 0) {
                    Cf[(size_t)(row0 + rowl) * N + col0 + coll] = val;
                } else {
                    const int R = row0 + rowl;
                    const int b = R >> 11, t = R & 2047;
                    const int CN = col0 + coll;
                    const int sec = CN >> 10, head = (CN >> 6) & 15, d = CN & 63;
                    const size_t off = (((size_t)(b * 16 + head)) * TSEQ + t) * 64 + d;
                    if (sec == 0)      Qb[off] = bf16bits(val * 0.125f);
                    else if (sec == 1) Kb[off] = bf16bits(fake_quant(val, qsc, qzp));
                    else               Vb[off] = bf16bits(fake_quant(val, qsc, qzp));
                }
            }
        }
}

// ---------------- MFMA flash attention (counted-vmcnt 2-buf pipeline) ----------------
// r10-proven body + r14 boustrophedon qt map (measured neutral, kept).
__global__ __launch_bounds__(256)
void mfma_attn_kernel(const ushort_t* __restrict__ Qb,   // [bh][T][64] (x0.125)
                      const ushort_t* __restrict__ Kq,   // [bh][T][64]
                      const ushort_t* __restrict__ Vtq,  // [bh][64][T]
                      ushort_t* __restrict__ outb) {     // [B][T][1024] bf16
    const int bx = blockIdx.x;
    const int bh = bx & 31;
    const int g = (bx >> 5) & 7, band = bx >> 8;
    const int qt = (band == 0) ? 31 - g
                 : (band == 1) ? 16 + g
                 : (band == 2) ? 15 - g
                 :               g;
    const int b = bh >> 4, h = bh & 15;
    const int tid = threadIdx.x;
    const int lane = tid & 63, w = tid >> 6;
    const int m16 = lane & 15, qc = lane >> 4;
    const int m7 = m16 & 7;

    __shared__ ushort_t Ks[2][4096];
    __shared__ ushort_t Vs[2][4096];
    __shared__ ushort_t Ps[4096];

    const int s_g = (lane & 7) ^ ((lane >> 3) & 7);
    const int s_r = lane >> 3;

    const ushort_t* Qg = Qb + (size_t)bh * TSEQ * 64;
    const ushort_t* Kg = Kq + (size_t)bh * TSEQ * 64;
    const ushort_t* Vg = Vtq + (size_t)bh * 64 * TSEQ;

    auto stageKV = [&](int buf, int kt) {
        #pragma unroll
        for (int pp = 0; pp < 2; ++pp) {
            const int p = 2 * w + pp;
            const ushort_t* gk = Kg + ((size_t)(kt * 64 + 8 * p + s_r)) * 64 + s_g * 8;
            __builtin_amdgcn_global_load_lds(
                (const __attribute__((address_space(1))) void*)gk,
                (__attribute__((address_space(3))) void*)(Ks[buf] + p * 512), 16, 0, 0);
            const ushort_t* gv = Vg + ((size_t)(8 * p + s_r)) * TSEQ + kt * 64 + s_g * 8;
            __builtin_amdgcn_global_load_lds(
                (const __attribute__((address_space(1))) void*)gv,
                (__attribute__((address_space(3))) void*)(Vs[buf] + p * 512), 16, 0, 0);
        }
    };

    stageKV(0, 0);

    // Q fragment straight from global: Q[qt*64 + 16w + m16][(qc+4c)*8 .. +7]
    bf16x8 a_q[2];
    {
        const ushort_t* qrow = Qg + (size_t)(qt * 64 + 16 * w + m16) * 64;
        a_q[0] = *(const bf16x8*)(qrow + qc * 8);
        a_q[1] = *(const bf16x8*)(qrow + (qc + 4) * 8);
    }

    float m_st[4], l_st[4];
    f32x4 o_acc[4];
    #pragma unroll
    for (int r = 0; r < 4; ++r) { m_st[r] = -INFINITY; l_st[r] = 0.0f; }
    #pragma unroll
    for (int dj = 0; dj < 4; ++dj) o_acc[dj] = (f32x4){0.f, 0.f, 0.f, 0.f};

    for (int kt = 0; kt <= qt; ++kt) {
        const int cur = kt & 1;
        if (kt < qt) {
            stageKV(cur ^ 1, kt + 1);
            asm volatile("s_waitcnt vmcnt(4)" ::: "memory");   // stage(kt) done; prefetch in flight
        } else {
            asm volatile("s_waitcnt vmcnt(0)" ::: "memory");   // last tile: drain stage(qt)
        }
        __builtin_amdgcn_s_barrier();   // B1: Ks/Vs[cur] fully written

        const bool diag = (kt == qt);
        const int nj_hi = diag ? (w + 1) : 4;

        f32x4 s[4];
        #pragma unroll
        for (int nj = 0; nj < 4; ++nj) s[nj] = (f32x4){0.f, 0.f, 0.f, 0.f};
        #pragma unroll
        for (int c = 0; c < 2; ++c) {
            #pragma unroll
            for (int nj = 0; nj < 4; ++nj) {
                if (nj < nj_hi) {
                    const int row = 16 * nj + m16;
                    const int gg = qc + 4 * c;
                    bf16x8 bk = *(const bf16x8*)((const char*)Ks[cur] + row * 128 + ((gg ^ m7) << 4));
                    s[nj] = __builtin_amdgcn_mfma_f32_16x16x32_bf16(a_q[c], bk, s[nj], 0, 0, 0);
                }
            }
        }

        float alpha[4], p_[4][4];
        #pragma unroll
        for (int reg = 0; reg < 4; ++reg) {
            const int qrow = 16 * w + 4 * qc + reg;
            float sv[4];
            float rm = -INFINITY;
            #pragma unroll
            for (int nj = 0; nj < 4; ++nj) {
                float v = s[nj][reg];
                if (diag && (m16 + 16 * nj > qrow)) v = -INFINITY;
                sv[nj] = v;
                rm = fmaxf(rm, v);
            }
            #pragma unroll
            for (int off = 1; off < 16; off <<= 1)
                rm = fmaxf(rm, __shfl_xor(rm, off, 16));
            const float mo = m_st[reg];
            const float mn = fmaxf(mo, rm);
            const float al = __expf(mo - mn);
            float rs = 0.f;
            #pragma unroll
            for (int nj = 0; nj < 4; ++nj) {
                float pv = __expf(sv[nj] - mn);
                p_[reg][nj] = pv;
                rs += pv;
            }
            #pragma unroll
            for (int off = 1; off < 16; off <<= 1)
                rs += __shfl_xor(rs, off, 16);
            l_st[reg] = al * l_st[reg] + rs;
            m_st[reg] = mn;
            alpha[reg] = al;
        }

        #pragma unroll
        for (int reg = 0; reg < 4; ++reg) {
            const int row = 16 * w + 4 * qc + reg;
            const int r7 = row & 7;
            #pragma unroll
            for (int nj = 0; nj < 4; ++nj) {
                const int k = m16 + 16 * nj;
                Ps[row * 64 + (((k >> 3) ^ r7) << 3) + (k & 7)] = bf16bits(p_[reg][nj]);
            }
        }

        #pragma unroll
        for (int dj = 0; dj < 4; ++dj)
            #pragma unroll
            for (int reg = 0; reg < 4; ++reg)
                o_acc[dj][reg] *= alpha[reg];

        const int c_hi = diag ? (w >= 2 ? 2 : 1) : 2;
        #pragma unroll
        for (int c = 0; c < 2; ++c) {
            if (c < c_hi) {
                const int rowp = 16 * w + m16;
                const int gg = qc + 4 * c;
                bf16x8 ap = *(const bf16x8*)((const char*)Ps + rowp * 128 + ((gg ^ m7) << 4));
                #pragma unroll
                for (int dj = 0; dj < 4; ++dj) {
                    const int rowv = 16 * dj + m16;
                    bf16x8 bv = *(const bf16x8*)((const char*)Vs[cur] + rowv * 128 + ((gg ^ m7) << 4));
                    o_acc[dj] = __builtin_amdgcn_mfma_f32_16x16x32_bf16(ap, bv, o_acc[dj], 0, 0, 0);
                }
            }
        }
        asm volatile("s_barrier" ::: "memory");   // B2: all waves done with buf[cur]
    }

    #pragma unroll
    for (int reg = 0; reg < 4; ++reg) {
        const float inv = 1.0f / l_st[reg];
        const int q = qt * 64 + 16 * w + 4 * qc + reg;
        #pragma unroll
        for (int dj = 0; dj < 4; ++dj) {
            const int d = m16 + 16 * dj;
            outb[((size_t)b * TSEQ + q) * N_EMBD + h * 64 + d] = bf16bits(o_acc[dj][reg] * inv);
        }
    }
}

extern "C" void kernel_launch(void* const* d_in, const int* in_sizes, int n_in,
                              void* d_out, int out_size, void* d_ws, size_t ws_size,
                              hipStream_t stream) {
    const float* x        = (const float*)d_in[0];
    const float* w_attn   = (const float*)d_in[1];
    const float* b_attn   = (const float*)d_in[2];
    const float* la_attn  = (const float*)d_in[3];
    const float* lb_attn  = (const float*)d_in[4];
    const float* w_proj   = (const float*)d_in[5];
    const float* b_proj   = (const float*)d_in[6];
    const float* la_proj  = (const float*)d_in[7];
    const float* lb_proj  = (const float*)d_in[8];
    const float* kv_scale = (const float*)d_in[9];
    const float* kv_zp    = (const float*)d_in[10];
    float* out = (float*)d_out;

    char* ws = (char*)d_ws;
    float* t_attn_p       = (float*)ws;          ws += (size_t)4 * M_TOTAL * RANK * 4;
    float* t_proj_p       = (float*)ws;          ws += (size_t)4 * M_TOTAL * RANK * 4;
    ushort_t* aob         = (ushort_t*)ws;       ws += (size_t)M_TOTAL * N_EMBD * 2;
    __hip_bfloat16* x_hi  = (__hip_bfloat16*)ws; ws += (size_t)M_TOTAL * N_EMBD * 2;
    __hip_bfloat16* x_lo  = (__hip_bfloat16*)ws; ws += (size_t)M_TOTAL * N_EMBD * 2;
    __hip_bfloat16* wqT_h = (__hip_bfloat16*)ws; ws += (size_t)C3 * N_EMBD * 2;
    __hip_bfloat16* wqT_l = (__hip_bfloat16*)ws; ws += (size_t)C3 * N_EMBD * 2;
    __hip_bfloat16* wpT   = (__hip_bfloat16*)ws; ws += (size_t)N_EMBD * N_EMBD * 2;
    ushort_t* Qb          = (ushort_t*)ws;       ws += (size_t)32 * TSEQ * 64 * 2;
    ushort_t* Kb          = (ushort_t*)ws;       ws += (size_t)32 * TSEQ * 64 * 2;
    ushort_t* Vb          = (ushort_t*)ws;       ws += (size_t)32 * TSEQ * 64 * 2;
    ushort_t* Vtq         = (ushort_t*)ws;       ws += (size_t)32 * 64 * TSEQ * 2;

    // fused prep: lora + transpose(w_attn) + transpose(w_proj) + cvt_split
    prep_kernel<<<dim3(NB_LORA + NB_TRA + NB_TRP + NB_CVT), 256, 0, stream>>>(
        x, w_attn, w_proj, la_attn,
        x_hi, x_lo, wqT_h, wqT_l, wpT, t_attn_p);

    // QKV: split only V columns (col0 >= 2048); 128x128 tiles, balanced map.
    gemm_mfma_kernel<true, 128, 128><<<dim3(24, 32), 256, 0, stream>>>(
        x_hi, x_lo, wqT_h, wqT_l, b_attn, t_attn_p, lb_attn,
        nullptr, Qb, Kb, Vb, kv_scale, kv_zp,
        M_TOTAL, C3, N_EMBD, 2 * N_EMBD, 1);

    vtrans_kernel<<<dim3(32 * (TSEQ / 64)), 256, 0, stream>>>(Vb, Vtq);

    mfma_attn_kernel<<<dim3(32 * 32), 256, 0, stream>>>(Qb, Kb, Vtq, aob);

    lora_t_part_bf16_kernel<<<dim3(M_TOTAL / 16, 4), 256, 0, stream>>>(aob, la_proj, t_proj_p, N_EMBD);

    // proj: 64x128 tiles -> 512 blocks = 2/CU (r8-proven best for proj)
    gemm_mfma_kernel<false, 64, 128><<<dim3(8, 64), 256, 0, stream>>>(
        (const __hip_bfloat16*)aob, nullptr, wpT, nullptr, b_proj, t_proj_p, lb_proj,
        out, nullptr, nullptr, nullptr, nullptr, nullptr,
        M_TOTAL, N_EMBD, N_EMBD, 1 << 30, 0);
}